// Round 5
// baseline (1778.871 us; speedup 1.0000x reference)
//
#include <hip/hip_runtime.h>
#include <math.h>

#define BB 512
#define SS 16
#define HH 501
#define KP 512
#define CC 7
#define OFF_ENC (BB*SS*SS)

// ws layout (float offsets)
#define O_BUFIN 0
#define O_BUFH  (KP*BB)
#define O_WHH   (2*KP*BB)                 // [3*KP][KP] padded Whh
#define O_WPOST (O_WHH + 3*KP*KP)         // [2*KP][KP] padded Wgate,Wmap
#define O_WLIN  (O_WPOST + 2*KP*KP)       // [KP][KP]  padded Wlin1
#define O_WDOT  (O_WLIN + KP*KP)          // [9][KP]   Wedge(2) + Wvert(7)
#define O_ALIST (O_WDOT + 9*KP)           // SS*BB
#define O_ELIST (O_ALIST + SS*BB)         // SS*BB
#define O_CLS   (O_ELIST + SS*BB)         // SS*BB ints

// ---------------- prep: transpose z, pad weights, cls, zero out regions -----
__global__ __launch_bounds__(256) void k_prep(
    const float* __restrict__ z, const float* __restrict__ xenc,
    const float* __restrict__ Wlin1, const float* __restrict__ Wgate,
    const float* __restrict__ Wmap,  const float* __restrict__ Whh,
    const float* __restrict__ Wedge, const float* __restrict__ Wvert,
    float* __restrict__ ws, float* __restrict__ out)
{
    const int b = blockIdx.x, tid = threadIdx.x;
    float* bufIn = ws + O_BUFIN;
    float* bufH  = ws + O_BUFH;
    if (b < 256) {
        // transpose z[512][501] -> bufH[KP][512]
        __shared__ float t[32][33];
        const int bt = b >> 4, kt = b & 15;
        const int b0 = bt * 32, k0 = kt * 32;
        const int tx = tid & 31, ty = tid >> 5;
#pragma unroll
        for (int i = 0; i < 4; ++i) {
            int row = ty + i * 8;
            if (k0 + tx < HH) t[row][tx] = z[(b0 + row) * HH + k0 + tx];
        }
        __syncthreads();
#pragma unroll
        for (int i = 0; i < 4; ++i) {
            int row = ty + i * 8;
            if (k0 + row < HH) bufH[(k0 + row) * BB + b0 + tx] = t[tx][row];
        }
    } else if (b == 256) {
        // zero pad rows HH..KP-1 of both act buffers
        for (int q = tid; q < (KP - HH) * BB; q += 256) {
            bufH[HH * BB + q] = 0.f;
            bufIn[HH * BB + q] = 0.f;
        }
    } else if (b < 265) {
        int* cls = (int*)(ws + O_CLS);
        int base = (b - 257) * 1024 + tid * 4;
#pragma unroll
        for (int q = 0; q < 4; ++q) {
            int e = base + q; int s = e >> 9, bb = e & 511;
            const float* xp = xenc + (bb * SS + s) * CC;
            int c = 0;
#pragma unroll
            for (int cc = 0; cc < CC; ++cc) if (xp[cc] > 0.5f) c = cc;
            cls[s * BB + bb] = c;
        }
    } else if (b < 297) {
        float4 z4 = make_float4(0.f, 0.f, 0.f, 0.f);
        float4* o4 = (float4*)out;
#pragma unroll
        for (int q = 0; q < 4; ++q)
            o4[(b - 265) * 1024 + q * 256 + tid] = z4;
    } else if (b < 425) {
        // padded weight copies: 128 blocks x 24 rows = 3072 = 6*KP rows
        int j0 = (b - 297) * 24;
        for (int jj = 0; jj < 24; ++jj) {
            int j = j0 + jj;
            const float* src; float* dst; int r;
            if (j < 3 * KP) {
                int gate = j / KP; r = j % KP;
                src = Whh + (gate * HH + min(r, HH - 1)) * HH;
                dst = ws + O_WHH + j * KP;
            } else if (j < 5 * KP) {
                int j2 = j - 3 * KP; int t2 = j2 / KP; r = j2 % KP;
                src = (t2 ? Wmap : Wgate) + min(r, HH - 1) * HH;
                dst = ws + O_WPOST + j2 * KP;
            } else {
                r = j - 5 * KP;
                src = Wlin1 + min(r, HH - 1) * HH;
                dst = ws + O_WLIN + r * KP;
            }
            bool zr = (r >= HH);
            for (int kk = tid; kk < KP; kk += 256)
                dst[kk] = (!zr && kk < HH) ? src[kk] : 0.f;
        }
    } else {
        for (int j = 0; j < 9; ++j) {
            const float* src = (j < 2) ? (Wedge + j * HH) : (Wvert + (j - 2) * HH);
            for (int kk = tid; kk < KP; kk += 256)
                ws[O_WDOT + j * KP + kk] = (kk < HH) ? src[kk] : 0.f;
        }
    }
}

// XCD-swizzled decode: x=bidx&7 picks row-slice; same x -> same rows every step
__device__ __forceinline__ void decode_gc(int bidx, int tid, int rows_per_g,
                                          int& g, int& col, int& rsub)
{
    int x = bidx & 7, q = bidx >> 3;
    int ch = q & 3;
    g = ((q >> 2) << 3) | x;
    col = ch * 128 + (tid & 127);
    rsub = __builtin_amdgcn_readfirstlane(tid >> 7);
    (void)rows_per_g;
}

// ---------------- g0 = (z @ Wlin1^T + b)^T : bufH(zT) -> bufIn --------------
__global__ __launch_bounds__(256) void k_g0(
    const float* __restrict__ act, const float* __restrict__ W,
    const float* __restrict__ blin1, float* __restrict__ dst)
{
    int g, col, rsub;
    decode_gc(blockIdx.x, threadIdx.x, 8, g, col, rsub);
    const int r0 = g * 8 + rsub * 4;                   // 4 rows/thread, r0<=508
    const float* wp[4];
#pragma unroll
    for (int i = 0; i < 4; ++i) wp[i] = W + (r0 + i) * KP;
    const float* ap = act + col;
    float a[4][8];
#pragma unroll
    for (int c = 0; c < 4; ++c)
#pragma unroll
        for (int s = 0; s < 8; ++s) a[c][s] = ap[(c * 8 + s) * BB];
    float acc[4] = {};
#pragma unroll 4
    for (int kc = 0; kc < 64; ++kc) {
        const int kb = kc * 8;
        float cur[8];
#pragma unroll
        for (int s = 0; s < 8; ++s) cur[s] = a[kc & 3][s];
#pragma unroll
        for (int s = 0; s < 8; ++s) a[kc & 3][s] = ap[((kc + 4) * 8 + s) * BB];
#pragma unroll
        for (int i = 0; i < 4; ++i) {
            float4 w0 = *(const float4*)(wp[i] + kb);
            float4 w1 = *(const float4*)(wp[i] + kb + 4);
            acc[i] = fmaf(w0.x, cur[0], acc[i]); acc[i] = fmaf(w0.y, cur[1], acc[i]);
            acc[i] = fmaf(w0.z, cur[2], acc[i]); acc[i] = fmaf(w0.w, cur[3], acc[i]);
            acc[i] = fmaf(w1.x, cur[4], acc[i]); acc[i] = fmaf(w1.y, cur[5], acc[i]);
            acc[i] = fmaf(w1.z, cur[6], acc[i]); acc[i] = fmaf(w1.w, cur[7], acc[i]);
        }
    }
#pragma unroll
    for (int i = 0; i < 4; ++i) {
        int r = r0 + i;
        if (r < HH) dst[r * BB + col] = acc[i] + blin1[r];
    }
}

// ---------------- GRU: bufIn(hin) -> bufH(h) --------------------------------
__global__ __launch_bounds__(256) void k_gru(
    const float* __restrict__ act, const float* __restrict__ W,
    const int* __restrict__ cls,
    const float* __restrict__ bhh, const float* __restrict__ Wih,
    const float* __restrict__ bih, int idx,
    float* __restrict__ dst)
{
    int g, col, rsub;
    decode_gc(blockIdx.x, threadIdx.x, 4, g, col, rsub);
    const int r0 = g * 4 + rsub * 2;                   // 2 h-rows/thread, r0<=510
    const float* wp[6];
#pragma unroll
    for (int gg = 0; gg < 3; ++gg)
#pragma unroll
        for (int rr = 0; rr < 2; ++rr)
            wp[gg * 2 + rr] = W + (gg * KP + r0 + rr) * KP;
    const float* ap = act + col;
    const int c = cls[idx * BB + col];
    float hprev[2] = { act[r0 * BB + col], act[(r0 + 1) * BB + col] };
    float a[4][8];
#pragma unroll
    for (int cc = 0; cc < 4; ++cc)
#pragma unroll
        for (int s = 0; s < 8; ++s) a[cc][s] = ap[(cc * 8 + s) * BB];
    float acc[6] = {};
#pragma unroll 4
    for (int kc = 0; kc < 64; ++kc) {
        const int kb = kc * 8;
        float cur[8];
#pragma unroll
        for (int s = 0; s < 8; ++s) cur[s] = a[kc & 3][s];
#pragma unroll
        for (int s = 0; s < 8; ++s) a[kc & 3][s] = ap[((kc + 4) * 8 + s) * BB];
#pragma unroll
        for (int j = 0; j < 6; ++j) {
            float4 w0 = *(const float4*)(wp[j] + kb);
            float4 w1 = *(const float4*)(wp[j] + kb + 4);
            acc[j] = fmaf(w0.x, cur[0], acc[j]); acc[j] = fmaf(w0.y, cur[1], acc[j]);
            acc[j] = fmaf(w0.z, cur[2], acc[j]); acc[j] = fmaf(w0.w, cur[3], acc[j]);
            acc[j] = fmaf(w1.x, cur[4], acc[j]); acc[j] = fmaf(w1.y, cur[5], acc[j]);
            acc[j] = fmaf(w1.z, cur[6], acc[j]); acc[j] = fmaf(w1.w, cur[7], acc[j]);
        }
    }
#pragma unroll
    for (int rr = 0; rr < 2; ++rr) {
        int r = r0 + rr;
        if (r < HH) {
            float gh0 = acc[0 + rr] + bhh[r];
            float gh1 = acc[2 + rr] + bhh[HH + r];
            float gh2 = acc[4 + rr] + bhh[2 * HH + r];
            float gi0 = Wih[r * CC + c] + bih[r];
            float gi1 = Wih[(HH + r) * CC + c] + bih[HH + r];
            float gi2 = Wih[(2 * HH + r) * CC + c] + bih[2 * HH + r];
            float rg = 1.f / (1.f + expf(-(gi0 + gh0)));
            float ug = 1.f / (1.f + expf(-(gi1 + gh1)));
            float ng = tanhf(gi2 + rg * gh2);
            dst[r * BB + col] = (1.f - ug) * ng + ug * hprev[rr];
        }
    }
}

// ---------------- post: bufH(h) -> bufIn(hin next) + dots/outputs -----------
__global__ __launch_bounds__(256) void k_post(
    const float* __restrict__ actH, const float* __restrict__ actIn,
    const float* __restrict__ Wp, const float* __restrict__ Wd,
    const float* __restrict__ bgate, const float* __restrict__ bmap,
    const float* __restrict__ dep,
    const float* __restrict__ bedge, const float* __restrict__ bvert,
    int idx, int ngemm, int dsrc,
    float* __restrict__ dst, float* __restrict__ Alist,
    float* __restrict__ Elist, float* __restrict__ out)
{
    const int tid = threadIdx.x;
    if ((int)blockIdx.x < ngemm) {
        int g, col, rsub;
        decode_gc(blockIdx.x, tid, 4, g, col, rsub);
        const int r0 = g * 4 + rsub * 2;
        const float* wp[4];                 // [type*2+rr]
#pragma unroll
        for (int t2 = 0; t2 < 2; ++t2)
#pragma unroll
            for (int rr = 0; rr < 2; ++rr)
                wp[t2 * 2 + rr] = Wp + (t2 * KP + r0 + rr) * KP;
        const float* ap = actH + col;
        const float d = dep[col * (SS * SS) + (idx + 1) * SS + idx];
        float a[4][8];
#pragma unroll
        for (int cc = 0; cc < 4; ++cc)
#pragma unroll
            for (int s = 0; s < 8; ++s) a[cc][s] = ap[(cc * 8 + s) * BB];
        float acc[4] = {};
#pragma unroll 4
        for (int kc = 0; kc < 64; ++kc) {
            const int kb = kc * 8;
            float cur[8];
#pragma unroll
            for (int s = 0; s < 8; ++s) cur[s] = a[kc & 3][s];
#pragma unroll
            for (int s = 0; s < 8; ++s) a[kc & 3][s] = ap[((kc + 4) * 8 + s) * BB];
#pragma unroll
            for (int j = 0; j < 4; ++j) {
                float4 w0 = *(const float4*)(wp[j] + kb);
                float4 w1 = *(const float4*)(wp[j] + kb + 4);
                acc[j] = fmaf(w0.x, cur[0], acc[j]); acc[j] = fmaf(w0.y, cur[1], acc[j]);
                acc[j] = fmaf(w0.z, cur[2], acc[j]); acc[j] = fmaf(w0.w, cur[3], acc[j]);
                acc[j] = fmaf(w1.x, cur[4], acc[j]); acc[j] = fmaf(w1.y, cur[5], acc[j]);
                acc[j] = fmaf(w1.z, cur[6], acc[j]); acc[j] = fmaf(w1.w, cur[7], acc[j]);
            }
        }
#pragma unroll
        for (int rr = 0; rr < 2; ++rr) {
            int r = r0 + rr;
            if (r < HH) {
                float bgv = bgate[r], bmv = bmap[r];
                float yg = acc[0 + rr] + bgv;
                float ym = acc[2 + rr] + bmv;
                float f  = (1.f / (1.f + expf(-yg))) * ym;
                float c0 = (1.f / (1.f + expf(-bgv))) * bmv;
                dst[r * BB + col] = (d != 0.f) ? (f + 15.f * c0) : (16.f * c0);
            }
        }
    } else {
        const int db = ((int)blockIdx.x - ngemm) * 256 + tid;
        const float* hp = (dsrc ? actH : actIn) + db;
        float a[4][8];
#pragma unroll
        for (int cc = 0; cc < 4; ++cc)
#pragma unroll
            for (int s = 0; s < 8; ++s) a[cc][s] = hp[(cc * 8 + s) * BB];
        float p[9];
#pragma unroll
        for (int j = 0; j < 9; ++j) p[j] = 0.f;
#pragma unroll 4
        for (int kc = 0; kc < 64; ++kc) {
            const int kb = kc * 8;
            float cur[8];
#pragma unroll
            for (int s = 0; s < 8; ++s) cur[s] = a[kc & 3][s];
#pragma unroll
            for (int s = 0; s < 8; ++s) a[kc & 3][s] = hp[((kc + 4) * 8 + s) * BB];
#pragma unroll
            for (int j = 0; j < 9; ++j) {
                float4 w0 = *(const float4*)(Wd + j * KP + kb);
                float4 w1 = *(const float4*)(Wd + j * KP + kb + 4);
                p[j] = fmaf(w0.x, cur[0], p[j]); p[j] = fmaf(w0.y, cur[1], p[j]);
                p[j] = fmaf(w0.z, cur[2], p[j]); p[j] = fmaf(w0.w, cur[3], p[j]);
                p[j] = fmaf(w1.x, cur[4], p[j]); p[j] = fmaf(w1.y, cur[5], p[j]);
                p[j] = fmaf(w1.z, cur[6], p[j]); p[j] = fmaf(w1.w, cur[7], p[j]);
            }
        }
        if (idx >= 0) { Alist[idx * BB + db] = p[0]; Elist[idx * BB + db] = p[1]; }
        if (idx <= SS - 2) {
            float lv[CC]; float mx = -1e30f;
#pragma unroll
            for (int c = 0; c < CC; ++c) { lv[c] = p[2 + c] + bvert[c]; mx = fmaxf(mx, lv[c]); }
            float sum = 0.f; float ev[CC];
#pragma unroll
            for (int c = 0; c < CC; ++c) { ev[c] = expf(lv[c] - mx); sum += ev[c]; }
            float inv = 1.f / sum;
#pragma unroll
            for (int c = 0; c < CC; ++c)
                out[OFF_ENC + (db * SS + (idx + 1)) * CC + c] = ev[c] * inv;
        }
        if (idx >= 1) {
            float be = bedge[0];
            float aprev = Alist[(idx - 1) * BB + db], eprev = Elist[(idx - 1) * BB + db];
            out[db * SS * SS + idx * SS + (idx - 1)] =
                (aprev + eprev + be >= 0.f) ? 1.f : 0.f;
            for (int vj = 0; vj <= idx - 2; ++vj)
                out[db * SS * SS + idx * SS + vj] =
                    (p[0] + Elist[vj * BB + db] + be >= 0.f) ? 1.f : 0.f;
        }
    }
}

extern "C" void kernel_launch(void* const* d_in, const int* in_sizes, int n_in,
                              void* d_out, int out_size, void* d_ws, size_t ws_size,
                              hipStream_t stream)
{
    const float* z     = (const float*)d_in[0];
    const float* dep   = (const float*)d_in[1];
    const float* xenc  = (const float*)d_in[2];
    const float* Wlin1 = (const float*)d_in[3];
    const float* blin1 = (const float*)d_in[4];
    const float* Wvert = (const float*)d_in[5];
    const float* bvert = (const float*)d_in[6];
    const float* Wedge = (const float*)d_in[7];
    const float* bedge = (const float*)d_in[8];
    const float* Wgate = (const float*)d_in[9];
    const float* bgate = (const float*)d_in[10];
    const float* Wmap  = (const float*)d_in[11];
    const float* bmap  = (const float*)d_in[12];
    const float* Wih   = (const float*)d_in[13];
    const float* bih   = (const float*)d_in[14];
    const float* Whh   = (const float*)d_in[15];
    const float* bhh   = (const float*)d_in[16];
    float* out = (float*)d_out;

    float* ws    = (float*)d_ws;
    float* bufIn = ws + O_BUFIN;
    float* bufH  = ws + O_BUFH;
    float* WhhP  = ws + O_WHH;
    float* WpostP= ws + O_WPOST;
    float* WlinP = ws + O_WLIN;
    float* WdotP = ws + O_WDOT;
    float* Alist = ws + O_ALIST;
    float* Elist = ws + O_ELIST;
    int*   cls   = (int*)(ws + O_CLS);

    k_prep<<<426, 256, 0, stream>>>(z, xenc, Wlin1, Wgate, Wmap, Whh,
                                    Wedge, Wvert, ws, out);
    k_g0<<<256, 256, 0, stream>>>(bufH, WlinP, blin1, bufIn);
    // enc row 0 from g0 (dots only, src = bufIn)
    k_post<<<2, 256, 0, stream>>>(bufH, bufIn, WpostP, WdotP, bgate, bmap, dep,
                                  bedge, bvert, -1, 0, 0,
                                  bufIn, Alist, Elist, out);
    for (int idx = 0; idx < SS; ++idx) {
        k_gru<<<512, 256, 0, stream>>>(bufIn, WhhP, cls, bhh, Wih, bih, idx, bufH);
        int ng = (idx < SS - 1) ? 512 : 0;
        k_post<<<ng + 2, 256, 0, stream>>>(bufH, bufIn, WpostP, WdotP, bgate, bmap,
                                           dep, bedge, bvert, idx, ng, 1,
                                           bufIn, Alist, Elist, out);
    }
}

// Round 6
// 1312.005 us; speedup vs baseline: 1.3558x; 1.3558x over previous
//
#include <hip/hip_runtime.h>
#include <math.h>

#define BB 512
#define SS 16
#define HH 501
#define CC 7
#define CH 128                 // k chunks of 4
#define PBK (4*BB)             // floats per packed chunk = 2048
#define OFF_ENC (BB*SS*SS)

#define BUFSZ (132*PBK)        // 128 chunks + 4 cushion (depth-3 prefetch)
#define O_BUFIN 0
#define O_BUFH  BUFSZ
#define O_ALIST (2*BUFSZ)
#define O_ELIST (O_ALIST + SS*BB)
#define O_CLS   (O_ELIST + SS*BB)

__device__ __forceinline__ float4 ld4(const float* p) { return *(const float4*)p; }
__device__ __forceinline__ float sigm(float x) { return 1.f / (1.f + expf(-x)); }

// packed address of (k, b)
__device__ __forceinline__ int PACK(int k, int b) {
    return (k >> 2) * PBK + b * 4 + (k & 3);
}

// ---------------- prep: z -> packed zT (bufH), cls, zero dep region ---------
__global__ __launch_bounds__(256) void k_prep(
    const float* __restrict__ z, const float* __restrict__ xenc,
    float* __restrict__ bufH, int* __restrict__ cls, float* __restrict__ out)
{
    const int b = blockIdx.x, tid = threadIdx.x;
    if (b < 256) {
        __shared__ float t[32][33];
        const int bt = b >> 4, kt = b & 15;
        const int b0 = bt * 32, k0 = kt * 32;
        const int tx = tid & 31, ty = tid >> 5;
#pragma unroll
        for (int i = 0; i < 4; ++i) {
            int row = ty + i * 8;
            t[row][tx] = (k0 + tx < HH) ? z[(b0 + row) * HH + k0 + tx] : 0.f;
        }
        __syncthreads();
#pragma unroll
        for (int i = 0; i < 4; ++i) {
            int row = ty + i * 8;
            int k = k0 + row;
            float v = (k < HH) ? t[tx][row] : 0.f;
            bufH[PACK(k, b0 + tx)] = v;
        }
    } else if (b < 264) {
        int base = (b - 256) * 1024 + tid * 4;
#pragma unroll
        for (int q = 0; q < 4; ++q) {
            int e = base + q; int s = e >> 9, bb = e & 511;
            const float* xp = xenc + (bb * SS + s) * CC;
            int c = 0;
#pragma unroll
            for (int cc = 0; cc < CC; ++cc) if (xp[cc] > 0.5f) c = cc;
            cls[s * BB + bb] = c;
        }
    } else {
        float4 z4 = make_float4(0.f, 0.f, 0.f, 0.f);
        float4* o4 = (float4*)out;
#pragma unroll
        for (int q = 0; q < 4; ++q)
            o4[(b - 264) * 1024 + q * 256 + tid] = z4;
    }
}

// ---------------- g0 = (z @ Wlin1^T + b)^T packed : bufH -> bufIn -----------
__global__ __launch_bounds__(256) void k_g0(
    const float* __restrict__ act, const float* __restrict__ W,
    const float* __restrict__ blin1, float* __restrict__ dst)
{
    __shared__ float wl[4][520];
    const int tid = threadIdx.x, lane = tid & 63;
    const int wv = __builtin_amdgcn_readfirstlane(tid >> 6);
    const int rg = blockIdx.x >> 2, ch = blockIdx.x & 3;
    const int r = rg * 4 + wv;
#pragma unroll
    for (int j = 0; j < 4; ++j) {
        int rr = rg * 4 + j;
        const float* src = W + (size_t)min(rr, HH - 1) * HH;
        bool ok = rr < HH;
        for (int k = tid; k < 512; k += 256)
            wl[j][k] = (ok && k < HH) ? src[k] : 0.f;
    }
    __syncthreads();
    const int c0 = ch * 128 + lane, c1 = c0 + 64;
    const float* a0 = act + c0 * 4;
    const float* a1 = act + c1 * 4;
    float4 A0[4], A1[4], Wb[2];
#pragma unroll
    for (int q = 0; q < 3; ++q) { A0[q] = ld4(a0 + q * PBK); A1[q] = ld4(a1 + q * PBK); }
    Wb[0] = ld4(&wl[wv][0]);
    float s0 = 0.f, s1 = 0.f;
#pragma unroll 4
    for (int kc = 0; kc < CH; ++kc) {
        int kn = kc + 3;
        A0[kn & 3] = ld4(a0 + (size_t)kn * PBK);
        A1[kn & 3] = ld4(a1 + (size_t)kn * PBK);
        int kw = min(kc + 1, CH - 1);
        Wb[(kc + 1) & 1] = ld4(&wl[wv][kw * 4]);
        float4 w = Wb[kc & 1], x0 = A0[kc & 3], x1 = A1[kc & 3];
        s0 = fmaf(w.x, x0.x, s0); s0 = fmaf(w.y, x0.y, s0);
        s0 = fmaf(w.z, x0.z, s0); s0 = fmaf(w.w, x0.w, s0);
        s1 = fmaf(w.x, x1.x, s1); s1 = fmaf(w.y, x1.y, s1);
        s1 = fmaf(w.z, x1.z, s1); s1 = fmaf(w.w, x1.w, s1);
    }
    if (r < HH) {
        float bv = blin1[r];
        dst[PACK(r, c0)] = s0 + bv;
        dst[PACK(r, c1)] = s1 + bv;
    }
}

// ---------------- GRU: bufIn(hin, packed) -> bufH(h, packed) ----------------
__global__ __launch_bounds__(256) void k_gru(
    const float* __restrict__ act, const float* __restrict__ Whh,
    const int* __restrict__ cls,
    const float* __restrict__ bhh, const float* __restrict__ Wih,
    const float* __restrict__ bih, int idx, float* __restrict__ dst)
{
    __shared__ float wl[12][520];
    const int tid = threadIdx.x, lane = tid & 63;
    const int wv = __builtin_amdgcn_readfirstlane(tid >> 6);
    const int rg = blockIdx.x >> 2, ch = blockIdx.x & 3;
    const int r = rg * 4 + wv;
#pragma unroll
    for (int j = 0; j < 12; ++j) {
        int g = j >> 2, rl = j & 3, rr = rg * 4 + rl;
        const float* src = Whh + (size_t)(g * HH + min(rr, HH - 1)) * HH;
        bool ok = rr < HH;
        for (int k = tid; k < 512; k += 256)
            wl[j][k] = (ok && k < HH) ? src[k] : 0.f;
    }
    const int c0 = ch * 128 + lane, c1 = c0 + 64;
    const int cc0 = cls[idx * BB + c0], cc1 = cls[idx * BB + c1];
    const float hp0 = act[PACK(min(r, HH - 1), c0)];
    const float hp1 = act[PACK(min(r, HH - 1), c1)];
    __syncthreads();
    const float* a0 = act + c0 * 4;
    const float* a1 = act + c1 * 4;
    float4 A0[4], A1[4], Wb[2][3];
#pragma unroll
    for (int q = 0; q < 3; ++q) { A0[q] = ld4(a0 + q * PBK); A1[q] = ld4(a1 + q * PBK); }
#pragma unroll
    for (int g = 0; g < 3; ++g) Wb[0][g] = ld4(&wl[g * 4 + wv][0]);
    float acc[6] = {};   // [gate*2 + col]
#pragma unroll 4
    for (int kc = 0; kc < CH; ++kc) {
        int kn = kc + 3;
        A0[kn & 3] = ld4(a0 + (size_t)kn * PBK);
        A1[kn & 3] = ld4(a1 + (size_t)kn * PBK);
        int kw = min(kc + 1, CH - 1);
#pragma unroll
        for (int g = 0; g < 3; ++g) Wb[(kc + 1) & 1][g] = ld4(&wl[g * 4 + wv][kw * 4]);
        float4 x0 = A0[kc & 3], x1 = A1[kc & 3];
#pragma unroll
        for (int g = 0; g < 3; ++g) {
            float4 w = Wb[kc & 1][g];
            acc[g*2+0] = fmaf(w.x, x0.x, acc[g*2+0]); acc[g*2+0] = fmaf(w.y, x0.y, acc[g*2+0]);
            acc[g*2+0] = fmaf(w.z, x0.z, acc[g*2+0]); acc[g*2+0] = fmaf(w.w, x0.w, acc[g*2+0]);
            acc[g*2+1] = fmaf(w.x, x1.x, acc[g*2+1]); acc[g*2+1] = fmaf(w.y, x1.y, acc[g*2+1]);
            acc[g*2+1] = fmaf(w.z, x1.z, acc[g*2+1]); acc[g*2+1] = fmaf(w.w, x1.w, acc[g*2+1]);
        }
    }
    if (r < HH) {
        float bi0 = bih[r], bi1 = bih[HH + r], bi2 = bih[2 * HH + r];
        float bh0 = bhh[r], bh1 = bhh[HH + r], bh2 = bhh[2 * HH + r];
        float w0c0 = Wih[(0 * HH + r) * CC + cc0], w1c0 = Wih[(1 * HH + r) * CC + cc0],
              w2c0 = Wih[(2 * HH + r) * CC + cc0];
        float w0c1 = Wih[(0 * HH + r) * CC + cc1], w1c1 = Wih[(1 * HH + r) * CC + cc1],
              w2c1 = Wih[(2 * HH + r) * CC + cc1];
        {
            float rgt = sigm(w0c0 + bi0 + acc[0] + bh0);
            float ugt = sigm(w1c0 + bi1 + acc[2] + bh1);
            float ngt = tanhf(w2c0 + bi2 + rgt * (acc[4] + bh2));
            dst[PACK(r, c0)] = (1.f - ugt) * ngt + ugt * hp0;
        }
        {
            float rgt = sigm(w0c1 + bi0 + acc[1] + bh0);
            float ugt = sigm(w1c1 + bi1 + acc[3] + bh1);
            float ngt = tanhf(w2c1 + bi2 + rgt * (acc[5] + bh2));
            dst[PACK(r, c1)] = (1.f - ugt) * ngt + ugt * hp1;
        }
    }
}

// ---------------- post: bufH(h) -> bufIn(next hin) + dots/outputs -----------
__global__ __launch_bounds__(256) void k_post(
    const float* __restrict__ actH, const float* __restrict__ actIn,
    const float* __restrict__ Wgate, const float* __restrict__ bgate,
    const float* __restrict__ Wmap,  const float* __restrict__ bmap,
    const float* __restrict__ dep,
    const float* __restrict__ Wedge, const float* __restrict__ bedge,
    const float* __restrict__ Wvert, const float* __restrict__ bvert,
    int idx, int ngemm, int dsrc,
    float* __restrict__ dst, float* __restrict__ Alist,
    float* __restrict__ Elist, float* __restrict__ out)
{
    __shared__ float wl[9][520];
    const int tid = threadIdx.x, lane = tid & 63;
    const int wv = __builtin_amdgcn_readfirstlane(tid >> 6);
    if ((int)blockIdx.x < ngemm) {
        const int rg = blockIdx.x >> 2, ch = blockIdx.x & 3;
        const int r = rg * 4 + wv;
#pragma unroll
        for (int j = 0; j < 8; ++j) {
            int t2 = j >> 2, rl = j & 3, rr = rg * 4 + rl;
            const float* src = (t2 ? Wmap : Wgate) + (size_t)min(rr, HH - 1) * HH;
            bool ok = rr < HH;
            for (int k = tid; k < 512; k += 256)
                wl[j][k] = (ok && k < HH) ? src[k] : 0.f;
        }
        const int c0 = ch * 128 + lane, c1 = c0 + 64;
        const float d0 = dep[c0 * (SS * SS) + (idx + 1) * SS + idx];
        const float d1 = dep[c1 * (SS * SS) + (idx + 1) * SS + idx];
        __syncthreads();
        const float* a0 = actH + c0 * 4;
        const float* a1 = actH + c1 * 4;
        float4 A0[4], A1[4], Wb[2][2];
#pragma unroll
        for (int q = 0; q < 3; ++q) { A0[q] = ld4(a0 + q * PBK); A1[q] = ld4(a1 + q * PBK); }
#pragma unroll
        for (int t2 = 0; t2 < 2; ++t2) Wb[0][t2] = ld4(&wl[t2 * 4 + wv][0]);
        float acc[4] = {};   // [type*2 + col]
#pragma unroll 4
        for (int kc = 0; kc < CH; ++kc) {
            int kn = kc + 3;
            A0[kn & 3] = ld4(a0 + (size_t)kn * PBK);
            A1[kn & 3] = ld4(a1 + (size_t)kn * PBK);
            int kw = min(kc + 1, CH - 1);
#pragma unroll
            for (int t2 = 0; t2 < 2; ++t2) Wb[(kc + 1) & 1][t2] = ld4(&wl[t2 * 4 + wv][kw * 4]);
            float4 x0 = A0[kc & 3], x1 = A1[kc & 3];
#pragma unroll
            for (int t2 = 0; t2 < 2; ++t2) {
                float4 w = Wb[kc & 1][t2];
                acc[t2*2+0] = fmaf(w.x, x0.x, acc[t2*2+0]); acc[t2*2+0] = fmaf(w.y, x0.y, acc[t2*2+0]);
                acc[t2*2+0] = fmaf(w.z, x0.z, acc[t2*2+0]); acc[t2*2+0] = fmaf(w.w, x0.w, acc[t2*2+0]);
                acc[t2*2+1] = fmaf(w.x, x1.x, acc[t2*2+1]); acc[t2*2+1] = fmaf(w.y, x1.y, acc[t2*2+1]);
                acc[t2*2+1] = fmaf(w.z, x1.z, acc[t2*2+1]); acc[t2*2+1] = fmaf(w.w, x1.w, acc[t2*2+1]);
            }
        }
        if (r < HH) {
            float bgv = bgate[r], bmv = bmap[r];
            float c0v = sigm(bgv) * bmv;
            float f0 = sigm(acc[0] + bgv) * (acc[2] + bmv);
            float f1 = sigm(acc[1] + bgv) * (acc[3] + bmv);
            dst[PACK(r, c0)] = (d0 != 0.f) ? (f0 + 15.f * c0v) : (16.f * c0v);
            dst[PACK(r, c1)] = (d1 != 0.f) ? (f1 + 15.f * c0v) : (16.f * c0v);
        }
    } else {
        // dot role: 2 blocks x 256 threads = 512 batch entries
#pragma unroll
        for (int j = 0; j < 9; ++j) {
            const float* src = (j < 2) ? (Wedge + j * HH) : (Wvert + (j - 2) * HH);
            for (int k = tid; k < 512; k += 256)
                wl[j][k] = (k < HH) ? src[k] : 0.f;
        }
        __syncthreads();
        const int db = ((int)blockIdx.x - ngemm) * 256 + tid;
        const float* hp = (dsrc ? actH : actIn) + db * 4;
        float4 Ab[4];
#pragma unroll
        for (int q = 0; q < 3; ++q) Ab[q] = ld4(hp + q * PBK);
        float p[9];
#pragma unroll
        for (int j = 0; j < 9; ++j) p[j] = 0.f;
#pragma unroll 4
        for (int kc = 0; kc < CH; ++kc) {
            int kn = kc + 3;
            Ab[kn & 3] = ld4(hp + (size_t)kn * PBK);
            float4 x = Ab[kc & 3];
#pragma unroll
            for (int j = 0; j < 9; ++j) {
                float4 w = ld4(&wl[j][kc * 4]);
                p[j] = fmaf(w.x, x.x, p[j]); p[j] = fmaf(w.y, x.y, p[j]);
                p[j] = fmaf(w.z, x.z, p[j]); p[j] = fmaf(w.w, x.w, p[j]);
            }
        }
        if (idx >= 0) { Alist[idx * BB + db] = p[0]; Elist[idx * BB + db] = p[1]; }
        if (idx <= SS - 2) {
            float lv[CC]; float mx = -1e30f;
#pragma unroll
            for (int c = 0; c < CC; ++c) { lv[c] = p[2 + c] + bvert[c]; mx = fmaxf(mx, lv[c]); }
            float sum = 0.f; float ev[CC];
#pragma unroll
            for (int c = 0; c < CC; ++c) { ev[c] = expf(lv[c] - mx); sum += ev[c]; }
            float inv = 1.f / sum;
#pragma unroll
            for (int c = 0; c < CC; ++c)
                out[OFF_ENC + (db * SS + (idx + 1)) * CC + c] = ev[c] * inv;
        }
        if (idx >= 1) {
            float be = bedge[0];
            float aprev = Alist[(idx - 1) * BB + db], eprev = Elist[(idx - 1) * BB + db];
            out[db * SS * SS + idx * SS + (idx - 1)] =
                (aprev + eprev + be >= 0.f) ? 1.f : 0.f;
            for (int vj = 0; vj <= idx - 2; ++vj)
                out[db * SS * SS + idx * SS + vj] =
                    (p[0] + Elist[vj * BB + db] + be >= 0.f) ? 1.f : 0.f;
        }
    }
}

extern "C" void kernel_launch(void* const* d_in, const int* in_sizes, int n_in,
                              void* d_out, int out_size, void* d_ws, size_t ws_size,
                              hipStream_t stream)
{
    const float* z     = (const float*)d_in[0];
    const float* dep   = (const float*)d_in[1];
    const float* xenc  = (const float*)d_in[2];
    const float* Wlin1 = (const float*)d_in[3];
    const float* blin1 = (const float*)d_in[4];
    const float* Wvert = (const float*)d_in[5];
    const float* bvert = (const float*)d_in[6];
    const float* Wedge = (const float*)d_in[7];
    const float* bedge = (const float*)d_in[8];
    const float* Wgate = (const float*)d_in[9];
    const float* bgate = (const float*)d_in[10];
    const float* Wmap  = (const float*)d_in[11];
    const float* bmap  = (const float*)d_in[12];
    const float* Wih   = (const float*)d_in[13];
    const float* bih   = (const float*)d_in[14];
    const float* Whh   = (const float*)d_in[15];
    const float* bhh   = (const float*)d_in[16];
    float* out = (float*)d_out;

    float* ws    = (float*)d_ws;
    float* bufIn = ws + O_BUFIN;
    float* bufH  = ws + O_BUFH;
    float* Alist = ws + O_ALIST;
    float* Elist = ws + O_ELIST;
    int*   cls   = (int*)(ws + O_CLS);

    k_prep<<<296, 256, 0, stream>>>(z, xenc, bufH, cls, out);
    k_g0<<<504, 256, 0, stream>>>(bufH, Wlin1, blin1, bufIn);
    // enc row 0 from g0 (dots only, src = bufIn)
    k_post<<<2, 256, 0, stream>>>(bufH, bufIn, Wgate, bgate, Wmap, bmap, dep,
                                  Wedge, bedge, Wvert, bvert, -1, 0, 0,
                                  bufIn, Alist, Elist, out);
    for (int idx = 0; idx < SS; ++idx) {
        k_gru<<<504, 256, 0, stream>>>(bufIn, Whh, cls, bhh, Wih, bih, idx, bufH);
        int ng = (idx < SS - 1) ? 504 : 0;
        k_post<<<ng + 2, 256, 0, stream>>>(bufH, bufIn, Wgate, bgate, Wmap, bmap,
                                           dep, Wedge, bedge, Wvert, bvert,
                                           idx, ng, 1,
                                           bufIn, Alist, Elist, out);
    }
}